// Round 5
// baseline (109.843 us; speedup 1.0000x reference)
//
#include <hip/hip_runtime.h>
#include <hip/hip_bf16.h>

#define M_TOT 32768
#define DDIM  1024
#define ODIM  768
#define LN_EPS 1e-5f

typedef __attribute__((__ext_vector_type__(8))) short bf16x8;
typedef __attribute__((__ext_vector_type__(4))) float f32x4;

__device__ __forceinline__ unsigned short f2bf(float f) {
  union { __hip_bfloat16 h; unsigned short u; } cv;
  cv.h = __float2bfloat16(f);
  return cv.u;
}

__device__ __forceinline__ float silu_f(float v) {
  return v / (1.f + __expf(-v));
}

__global__ void wconv_kernel(const float4* __restrict__ Wf, ushort4* __restrict__ Wb, int n4) {
  int i = blockIdx.x * blockDim.x + threadIdx.x;
  if (i >= n4) return;
  float4 v = Wf[i];
  ushort4 o;
  o.x = f2bf(v.x); o.y = f2bf(v.y); o.z = f2bf(v.z); o.w = f2bf(v.w);
  Wb[i] = o;
}

// ===================== kernel 1: LN + SiLU -> h (bf16) =====================
__global__ __launch_bounds__(256)
void ln_silu_kernel(const float* __restrict__ x, const float* __restrict__ lnw,
                    const float* __restrict__ lnb, __hip_bfloat16* __restrict__ h)
{
  const int tid  = threadIdx.x;
  const int lane = tid & 63;
  const int wid  = tid >> 6;
  const int row  = blockIdx.x * 4 + wid;

  const float4* xr = (const float4*)(x + (size_t)row * DDIM);
  float4 v[4];
#pragma unroll
  for (int jj = 0; jj < 4; ++jj) v[jj] = xr[lane + 64 * jj];

  float s = 0.f, ss = 0.f;
#pragma unroll
  for (int jj = 0; jj < 4; ++jj) {
    float4 a = v[jj];
    s  += a.x + a.y + a.z + a.w;
    ss += a.x * a.x + a.y * a.y + a.z * a.z + a.w * a.w;
  }
#pragma unroll
  for (int off = 1; off < 64; off <<= 1) {
    s  += __shfl_xor(s, off);
    ss += __shfl_xor(ss, off);
  }
  const float mean = s * (1.f / 1024.f);
  const float rstd = rsqrtf(ss * (1.f / 1024.f) - mean * mean + LN_EPS);

  ushort4* hr = (ushort4*)(h + (size_t)row * DDIM);
#pragma unroll
  for (int jj = 0; jj < 4; ++jj) {
    float4 wv = ((const float4*)lnw)[lane + 64 * jj];
    float4 bv = ((const float4*)lnb)[lane + 64 * jj];
    float4 a  = v[jj];
    float e0 = silu_f((a.x - mean) * rstd * wv.x + bv.x);
    float e1 = silu_f((a.y - mean) * rstd * wv.y + bv.y);
    float e2 = silu_f((a.z - mean) * rstd * wv.z + bv.z);
    float e3 = silu_f((a.w - mean) * rstd * wv.w + bv.w);
    ushort4 o; o.x = f2bf(e0); o.y = f2bf(e1); o.z = f2bf(e2); o.w = f2bf(e3);
    hr[lane + 64 * jj] = o;
  }
}

// ========== kernel 2: GEMM + rearrange, BM=256 phase-interleaved ring-3 ====
// BM=256, BN=192, BK=32; 512 thr = 8 waves (4M x 2N), wave C = 64x96.
// Ring-3 LDS 3 x 28 KB = 84 KB static. Per K-tile: 2 phases, each
// {stage-half(t+2), ds_read frags, 12 MFMA}; counted vmcnt(4/3); setprio.
#define GBM 256
#define GBN 192
#define ABY 16384          // 256 rows x 64 B
#define BUFB 28672         // ABY + 192*64
#define VMW(n) asm volatile("s_waitcnt vmcnt(" #n ")" ::: "memory")

__device__ __forceinline__ void gload16(const void* g, void* l) {
  __builtin_amdgcn_global_load_lds(
      (const __attribute__((address_space(1))) unsigned int*)g,
      (__attribute__((address_space(3))) unsigned int*)l, 16, 0, 0);
}

__global__ __launch_bounds__(512, 2)
void gemm_kernel(const __hip_bfloat16* __restrict__ h,
                 const __hip_bfloat16* __restrict__ Wb,
                 const float* __restrict__ bias,
                 float* __restrict__ out)
{
  __shared__ char smem[3 * BUFB];          // 86016 B static
  const int tid  = threadIdx.x;
  const int lane = tid & 63;
  const int w    = tid >> 6;

  // bijective XCD swizzle: 512 blocks, cpx=64
  const int wg = blockIdx.x;
  const int sv = ((wg & 7) << 6) + (wg >> 3);
  const int mt = sv >> 2, nt = sv & 3;
  const int m0 = mt << 8, n0 = nt * GBN;

  // ---- staging source pointers (pre-swizzled: 16B chunk ^= row&3) ----
  const int aR0 = tid >> 2;
  const __hip_bfloat16* aP0 = h + (size_t)(m0 + aR0) * DDIM + (((tid & 3) ^ (aR0 & 3)) << 3);
  const int s1  = 512 + tid;
  const int aR1 = s1 >> 2;
  const __hip_bfloat16* aP1 = h + (size_t)(m0 + aR1) * DDIM + (((s1 & 3) ^ (aR1 & 3)) << 3);
  const int bR0 = tid >> 2;
  const __hip_bfloat16* bP0 = Wb + (size_t)(n0 + bR0) * DDIM + (((tid & 3) ^ (bR0 & 3)) << 3);
  const int bR1 = s1 >> 2;
  const __hip_bfloat16* bP1 = Wb + (size_t)(n0 + bR1) * DDIM + (((s1 & 3) ^ (bR1 & 3)) << 3);
  const bool half = (tid < 256);           // wave-uniform (waves 0-3)

  // ---- MFMA fragment LDS read offsets (swizzle-matched, uniform banks) ----
  const int wm = w >> 1, wn = w & 1;       // 4M x 2N
  const int lr = lane & 15, lq = lane >> 4;
  int aRd[4], bRd[6];
#pragma unroll
  for (int i = 0; i < 4; ++i) {
    int row = wm * 64 + i * 16 + lr;
    aRd[i] = row * 64 + ((lq ^ (row & 3)) << 4);
  }
#pragma unroll
  for (int j = 0; j < 6; ++j) {
    int row = wn * 96 + j * 16 + lr;
    bRd[j] = ABY + row * 64 + ((lq ^ (row & 3)) << 4);
  }

  auto stP0 = [&](int t) {                 // 2 loads/thread
    const int k0 = t << 5;
    char* b = smem + (t % 3) * BUFB;
    gload16(aP0 + k0, b + (tid << 4));
    gload16(bP0 + k0, b + ABY + (tid << 4));
  };
  auto stP1 = [&](int t) {                 // 2 (waves 0-3) / 1 (waves 4-7)
    const int k0 = t << 5;
    char* b = smem + (t % 3) * BUFB;
    gload16(aP1 + k0, b + (s1 << 4));
    if (half) gload16(bP1 + k0, b + ABY + (s1 << 4));
  };

  f32x4 acc[4][6];
#pragma unroll
  for (int i = 0; i < 4; ++i)
#pragma unroll
    for (int j = 0; j < 6; ++j)
      acc[i][j] = (f32x4){0.f, 0.f, 0.f, 0.f};

  // prologue: 2 tiles in flight
  stP0(0); stP1(0); stP0(1); stP1(1);

  for (int t = 0; t < 32; ++t) {
    // wait for stage(t); only stage(t+1) may remain outstanding (per role)
    if (t < 31) { if (half) VMW(4); else VMW(3); }
    else        { VMW(0); }
    __builtin_amdgcn_s_barrier();
    asm volatile("" ::: "memory");

    const char* bb = smem + (t % 3) * BUFB;
    // ---- phase 0: stage half, read A + first B half, 12 MFMA ----
    if (t < 30) stP0(t + 2);
    bf16x8 af[4], bf0[3];
#pragma unroll
    for (int i = 0; i < 4; ++i) af[i]  = *(const bf16x8*)(bb + aRd[i]);
#pragma unroll
    for (int j = 0; j < 3; ++j) bf0[j] = *(const bf16x8*)(bb + bRd[j]);
    __builtin_amdgcn_s_setprio(1);
#pragma unroll
    for (int i = 0; i < 4; ++i)
#pragma unroll
      for (int j = 0; j < 3; ++j)
        acc[i][j] = __builtin_amdgcn_mfma_f32_16x16x32_bf16(af[i], bf0[j], acc[i][j], 0, 0, 0);
    __builtin_amdgcn_s_setprio(0);
    asm volatile("" ::: "memory");
    __builtin_amdgcn_s_barrier();          // mid-phase alignment
    asm volatile("" ::: "memory");
    // ---- phase 1: stage half, read second B half, 12 MFMA ----
    if (t < 30) stP1(t + 2);
    bf16x8 bf1[3];
#pragma unroll
    for (int j = 0; j < 3; ++j) bf1[j] = *(const bf16x8*)(bb + bRd[3 + j]);
    __builtin_amdgcn_s_setprio(1);
#pragma unroll
    for (int i = 0; i < 4; ++i)
#pragma unroll
      for (int j = 0; j < 3; ++j)
        acc[i][3 + j] = __builtin_amdgcn_mfma_f32_16x16x32_bf16(af[i], bf1[j], acc[i][3 + j], 0, 0, 0);
    __builtin_amdgcn_s_setprio(0);
  }

  // ---------- epilogue: LDS repack to output order, coalesced f4 stores ----
  // 16 chunks of 16 tokens; buffer [c(3)][pr(4)][tk(16)][pw(16)] f32 = 12 KB.
  // Bank spread: tk ^= c&1 (bank bit4), pw ^= lq<<2 (write lanes).
  const int b   = m0 >> 10;
  const int hq0 = (m0 & 1023) >> 5;
  float bv[6]; int cj[6], pwj[6], prj[6];
#pragma unroll
  for (int j = 0; j < 6; ++j) {
    int o = wn * 96 + j * 16 + lr;         // 0..191
    bv[j]  = bias[n0 + o];
    cj[j]  = o % 3;
    int oq = o / 3;
    pwj[j] = oq & 15;
    prj[j] = o / 48;                       // 0..3
  }
  float* ldsF = (float*)smem;

#pragma unroll
  for (int g = 0; g < 16; ++g) {
    if (wm == (g >> 2)) {
      const int i_f = g & 3;
#pragma unroll
      for (int j = 0; j < 6; ++j)
#pragma unroll
        for (int r = 0; r < 4; ++r) {
          const int tk = lq * 4 + r;
          ldsF[((cj[j] * 4 + prj[j]) << 8) + ((tk ^ (cj[j] & 1)) << 4) + (pwj[j] ^ (lq << 2))] =
              acc[i_f][j][r] + bv[j];
        }
    }
    __syncthreads();
    const int hh = hq0 + (g >> 1);
#pragma unroll
    for (int q = 0; q < 2; ++q) {
      if (q == 1 && tid >= 256) break;     // 768 f4 total
      const int f   = (q << 9) + tid;
      const int c   = f >> 8;
      const int pr  = (f >> 6) & 3;
      const int tk  = (f >> 2) & 15;
      const int pw0 = (f & 3) << 2;
      const int lqw = tk >> 2;
      float4 v = *(const float4*)(ldsF + (((c * 4 + pr) << 8) + ((tk ^ (c & 1)) << 4)
                                          + (pw0 ^ (lqw << 2))));
      const size_t idx = (((size_t)(b * 3 + c)) << 18)
                       + (size_t)((hh << 4) + (nt << 2) + pr) * 512
                       + ((g & 1) << 8) + (tk << 4) + pw0;
      *(float4*)(out + idx) = v;
    }
    __syncthreads();
  }
}

// ===================== fallback: fused (no workspace) =====================
#define BM 64
#define BK 32
#define NTHR 1024
#define LDS_BYTES 53760

__global__ __launch_bounds__(NTHR, 4)
void fused_kernel(const float* __restrict__ x,
                  const float* __restrict__ lnw,
                  const float* __restrict__ lnb,
                  const float* __restrict__ Wf,
                  const float* __restrict__ bias,
                  float* __restrict__ out)
{
  extern __shared__ char smem[];
  char* AsBase = smem;
  char* BsBase = smem + 4096;
  float* smean = (float*)(smem + 53248);
  float* srstd = smean + BM;

  const int tid = threadIdx.x;
  const int m0  = blockIdx.x * BM;
  const int bb   = m0 >> 10;
  const int h0   = (m0 & 1023) >> 5;

  {
    const int row = tid >> 4;
    const int sub = tid & 15;
    const float4* xr = (const float4*)(x + (size_t)(m0 + row) * DDIM);
    float s = 0.f, ss = 0.f;
#pragma unroll 4
    for (int j = 0; j < 16; ++j) {
      float4 v = xr[sub + (j << 4)];
      s  += v.x + v.y + v.z + v.w;
      ss += v.x * v.x + v.y * v.y + v.z * v.z + v.w * v.w;
    }
#pragma unroll
    for (int off = 1; off < 16; off <<= 1) {
      s  += __shfl_xor(s, off);
      ss += __shfl_xor(ss, off);
    }
    if (sub == 0) {
      float mean = s * (1.f / 1024.f);
      float var  = ss * (1.f / 1024.f) - mean * mean;
      smean[row] = mean;
      srstd[row] = rsqrtf(var + LN_EPS);
    }
  }
  __syncthreads();

  const int arow  = tid >> 4;
  const int acol2 = tid & 15;
  const int aOff  = (m0 + arow) * DDIM + (acol2 << 1);
  const int aDst  = (arow << 6) + ((((acol2 >> 2) ^ ((arow >> 2) & 3)) << 4)) + ((acol2 & 3) << 2);
  const float aMean = smean[arow];
  const float aRstd = srstd[arow];

  int bOffF[6], bDstF[6];
#pragma unroll
  for (int c = 0; c < 6; ++c) {
    int idx = tid + (c << 10);
    int r = idx >> 3, c4 = idx & 7;
    bOffF[c] = r * DDIM + (c4 << 2);
    bDstF[c] = (r << 6) + ((((c4 >> 1) ^ ((r >> 2) & 3)) << 4)) + ((c4 & 1) << 3);
  }

  const int lane = tid & 63;
  const int wid  = tid >> 6;
  const int lr   = lane & 15;
  const int lq   = lane >> 4;
  const int kswz = (lq ^ ((lr >> 2) & 3)) << 4;
  int aRd[4], bRd[3];
#pragma unroll
  for (int i = 0; i < 4; ++i) aRd[i] = (((i << 4) + lr) << 6) + kswz;
#pragma unroll
  for (int j = 0; j < 3; ++j) bRd[j] = ((wid * 48 + (j << 4) + lr) << 6) + kswz;

  float2 aReg, lwReg, lbReg;
  float4 bRegF[6];

  auto loadTile = [&](int tt) {
    const int k0 = tt * BK;
    aReg  = *(const float2*)(x + aOff + k0);
    lwReg = *(const float2*)(lnw + (acol2 << 1) + k0);
    lbReg = *(const float2*)(lnb + (acol2 << 1) + k0);
#pragma unroll
    for (int c = 0; c < 6; ++c)
      bRegF[c] = *(const float4*)(Wf + bOffF[c] + k0);
  };

  auto storeTile = [&]() {
    float hx = (aReg.x - aMean) * aRstd * lwReg.x + lbReg.x;
    float hy = (aReg.y - aMean) * aRstd * lwReg.y + lbReg.y;
    hx = silu_f(hx); hy = silu_f(hy);
    ushort2 ap; ap.x = f2bf(hx); ap.y = f2bf(hy);
    *(ushort2*)(AsBase + aDst) = ap;
#pragma unroll
    for (int c = 0; c < 6; ++c) {
      float4 wv = bRegF[c];
      ushort4 bp; bp.x = f2bf(wv.x); bp.y = f2bf(wv.y); bp.z = f2bf(wv.z); bp.w = f2bf(wv.w);
      *(ushort4*)(BsBase + bDstF[c]) = bp;
    }
  };

  f32x4 acc[4][3];
#pragma unroll
  for (int i = 0; i < 4; ++i)
#pragma unroll
    for (int j = 0; j < 3; ++j)
      acc[i][j] = (f32x4){0.f, 0.f, 0.f, 0.f};

  loadTile(0);
  storeTile();
  __syncthreads();

  for (int t = 0; t < 32; ++t) {
    if (t < 31) loadTile(t + 1);
    bf16x8 af[4], bfr[3];
#pragma unroll
    for (int i = 0; i < 4; ++i) af[i] = *(const bf16x8*)(AsBase + aRd[i]);
#pragma unroll
    for (int j = 0; j < 3; ++j) bfr[j] = *(const bf16x8*)(BsBase + bRd[j]);
#pragma unroll
    for (int i = 0; i < 4; ++i)
#pragma unroll
      for (int j = 0; j < 3; ++j)
        acc[i][j] = __builtin_amdgcn_mfma_f32_16x16x32_bf16(af[i], bfr[j], acc[i][j], 0, 0, 0);
    __syncthreads();
    if (t < 31) storeTile();
    __syncthreads();
  }

  float* ldsF = (float*)smem;
  float bv[3]; int cv[3], phv[3], pwv[3];
#pragma unroll
  for (int j = 0; j < 3; ++j) {
    const int o = wid * 48 + (j << 4) + lr;
    bv[j]  = bias[o];
    cv[j]  = o % 3;
    const int oq = o / 3;
    pwv[j] = oq & 15;
    phv[j] = oq >> 4;
  }

#pragma unroll
  for (int i = 0; i < 4; ++i) {
#pragma unroll
    for (int j = 0; j < 3; ++j) {
#pragma unroll
      for (int r = 0; r < 4; ++r) {
        const int wl  = (lq << 2) + r;
        const int lin = ((cv[j] * 16 + phv[j]) << 8) + (wl << 4) + pwv[j];
        const int dws = lin ^ (cv[j] << 2) ^ (((lin >> 6) & 1) << 4);
        ldsF[dws] = acc[i][j][r] + bv[j];
      }
    }
    __syncthreads();
    const int hq = h0 + (i >> 1);
    const int w0 = (i & 1) << 4;
#pragma unroll
    for (int q = 0; q < 3; ++q) {
      const int g4  = (q << 10) + tid;
      const int dw  = g4 << 2;
      const int run = dw >> 8;
      const int c   = run >> 4;
      const int ph  = run & 15;
      const int wl  = (dw >> 4) & 15;
      const int pw  = dw & 15;
      const int dws = dw ^ (c << 2) ^ (((dw >> 6) & 1) << 4);
      float4 v = *(const float4*)(ldsF + dws);
      const size_t idx = (((size_t)(bb * 3 + c)) << 18)
                       + ((size_t)((hq << 4) + ph) << 9)
                       + ((w0 + wl) << 4) + pw;
      *(float4*)(out + idx) = v;
    }
    __syncthreads();
  }
}

extern "C" void kernel_launch(void* const* d_in, const int* in_sizes, int n_in,
                              void* d_out, int out_size, void* d_ws, size_t ws_size,
                              hipStream_t stream) {
  const float* x    = (const float*)d_in[0];
  const float* lnw  = (const float*)d_in[1];
  const float* lnb  = (const float*)d_in[2];
  const float* W    = (const float*)d_in[3];
  const float* bias = (const float*)d_in[4];
  float* out = (float*)d_out;

  const size_t wbBytes = (size_t)ODIM * DDIM * sizeof(__hip_bfloat16);   // 1.5 MB
  const size_t hBytes  = (size_t)M_TOT * DDIM * sizeof(__hip_bfloat16);  // 64 MB
  __hip_bfloat16* Wb = (__hip_bfloat16*)d_ws;
  __hip_bfloat16* hb = (__hip_bfloat16*)((char*)d_ws + wbBytes);

  if (ws_size >= wbBytes + hBytes) {
    wconv_kernel<<<dim3(768), dim3(256), 0, stream>>>((const float4*)W, (ushort4*)Wb,
                                                      ODIM * DDIM / 4);
    ln_silu_kernel<<<dim3(M_TOT / 4), dim3(256), 0, stream>>>(x, lnw, lnb, hb);
    gemm_kernel<<<dim3((M_TOT / GBM) * (ODIM / GBN)), dim3(512), 0, stream>>>(hb, Wb, bias, out);
  } else {
    fused_kernel<<<dim3(M_TOT / BM), dim3(NTHR), LDS_BYTES, stream>>>(
        x, lnw, lnb, W, bias, out);
  }
}